// Round 14
// baseline (2099.334 us; speedup 1.0000x reference)
//
#include <hip/hip_runtime.h>
#include <hip/hip_cooperative_groups.h>
#include <hip/hip_fp16.h>
#include <cstdint>
#include <cstddef>

namespace cg = cooperative_groups;

// Sinkhorn OT loss, B=4096, D=512.
// Round 11 (3rd resubmit): round-8 persistent structure; barrier fixed:
//  - poll epoch with RELAXED loads (no per-poll buffer_inv storm)
//  - ONE acquire fence after the barrier (per thread), then PLAIN float4
//    gathers of u/v (fence invalidated L1/L2 -> fresh from LLC)
//  - release side unchanged: u-stores are wave-0 lanes 0..15; thread0's
//    RELEASE fetch_add drains them via per-wave vmcnt.
// Scaling: Ks = K*2^26 fp8 e5m2, a~ = a*2^24,
//   loss = 2^-24 * sum u~ Ks v~ c, c = REG*(26 ln2 - ln Ks) via byte LUT.
// ws: Km 16MB @0 | KTm @16MB | bar @32MB (4KB) | uglob @32MB+4KB (16KB f32) |
//     vglob next | Xe @33MB | Ye @48MB | Xs,Ys @64MB

#define N_B 4096
#define N_D 512
#define KE  1536
#define REG_ 0.05f
#define LN2_ 0.693147180559945f
#define S_LOG 26.0f
#define A_SC 4096.0f                // (1/4096) * 2^24
#define EPS_U 0.067108864f          // 1e-9 * 2^26
#define EPS_V 0.016777216f          // 1e-9 * 2^24
#define OUT_SCALE 5.9604644775e-8f  // 2^-24
#define CSTR 32                     // barrier counter stride (128B)

typedef __attribute__((ext_vector_type(8))) short bs8;
typedef __attribute__((ext_vector_type(8))) unsigned short us8;
typedef __attribute__((ext_vector_type(4))) float f32x4;
typedef __attribute__((ext_vector_type(2))) _Float16 h2;
typedef __attribute__((ext_vector_type(8))) _Float16 h8;

__device__ __forceinline__ float bf2f(unsigned short u) {
  union { uint32_t i; float f; } x; x.i = ((uint32_t)u) << 16; return x.f;
}
__device__ __forceinline__ unsigned short f2bf(float f) {
  union { float f; uint32_t i; } x; x.f = f;
  uint32_t r = (x.i + 0x7FFFu + ((x.i >> 16) & 1u)) >> 16;
  return (unsigned short)r;
}
__device__ __forceinline__ unsigned char f2fp8(float f) {
  f = fminf(f, 57344.0f);
  __half h = __float2half(f);
  unsigned short hb = *(unsigned short*)&h;
  unsigned short r = (unsigned short)((hb + 0x7F + ((hb >> 8) & 1)) >> 8);
  return (unsigned char)r;
}
__device__ __forceinline__ h2 as_h2(uint32_t x) {
  union { uint32_t u; h2 h; } c; c.u = x; return c.h;
}
__device__ __forceinline__ float wave_reduce_sum(float x) {
#pragma unroll
  for (int off = 32; off > 0; off >>= 1) x += __shfl_down(x, off);
  return x;
}

__global__ __launch_bounds__(256) void prep_kernel(const float* __restrict__ X,
                                                   const float* __restrict__ Y,
                                                   unsigned short* __restrict__ Xe,
                                                   unsigned short* __restrict__ Ye) {
  int idx = (blockIdx.x * 256 + threadIdx.x) * 8;
  int row = idx >> 9, col = idx & 511;
  size_t base = (size_t)row * KE + col;
  float fx[8], fy[8];
  *(float4*)&fx[0] = *(const float4*)&X[idx];
  *(float4*)&fx[4] = *(const float4*)&X[idx + 4];
  *(float4*)&fy[0] = *(const float4*)&Y[idx];
  *(float4*)&fy[4] = *(const float4*)&Y[idx + 4];
  us8 xh, xl, yh, yl;
#pragma unroll
  for (int k = 0; k < 8; ++k) {
    unsigned short h = f2bf(fx[k]);
    xh[k] = h; xl[k] = f2bf(fx[k] - bf2f(h));
    unsigned short g = f2bf(fy[k]);
    yh[k] = g; yl[k] = f2bf(fy[k] - bf2f(g));
  }
  *(us8*)&Xe[base] = xh; *(us8*)&Xe[base + 512] = xl; *(us8*)&Xe[base + 1024] = xh;
  *(us8*)&Ye[base] = yh; *(us8*)&Ye[base + 512] = yh; *(us8*)&Ye[base + 1024] = yl;
}

__global__ __launch_bounds__(256) void rownorm_kernel(const float* __restrict__ X,
                                                      float* __restrict__ out) {
  int row = blockIdx.x * 4 + (threadIdx.x >> 6);
  int lane = threadIdx.x & 63;
  const float4* Xr = (const float4*)(X + (size_t)row * N_D);
  float acc = 0.f;
#pragma unroll
  for (int k = lane; k < N_D / 4; k += 64) {
    float4 a = Xr[k];
    acc += a.x * a.x + a.y * a.y + a.z * a.z + a.w * a.w;
  }
  acc = wave_reduce_sum(acc);
  if (lane == 0) out[row] = acc;
}

__global__ __launch_bounds__(256) void gemm_costK(const unsigned short* __restrict__ Xe,
                                                  const unsigned short* __restrict__ Ye,
                                                  const float* __restrict__ Xs,
                                                  const float* __restrict__ Ys,
                                                  unsigned char* __restrict__ Km) {
  __shared__ unsigned short As[128 * 32];
  __shared__ unsigned short Bs[128 * 32];
  const int tid = threadIdx.x;
  const int lane = tid & 63, w = tid >> 6;
  const int wr = w >> 1, wc = w & 1;
  const int row0 = blockIdx.y * 128, col0 = blockIdx.x * 128;

  f32x4 acc[4][4];
#pragma unroll
  for (int i = 0; i < 4; ++i)
#pragma unroll
    for (int j = 0; j < 4; ++j) acc[i][j] = (f32x4)(0.0f);

  const int srow = tid >> 2;
  const int scol = (tid & 3) * 8;

  for (int k0 = 0; k0 < KE; k0 += 32) {
#pragma unroll
    for (int c = 0; c < 2; ++c) {
      int r = srow + c * 64;
      const unsigned short* ga = Xe + (size_t)(row0 + r) * KE + k0 + scol;
      const unsigned short* gb = Ye + (size_t)(col0 + r) * KE + k0 + scol;
      char* la = (char*)As + c * 4096 + w * 1024;
      char* lb = (char*)Bs + c * 4096 + w * 1024;
      __builtin_amdgcn_global_load_lds((const __attribute__((address_space(1))) void*)ga,
                                       (__attribute__((address_space(3))) void*)la, 16, 0, 0);
      __builtin_amdgcn_global_load_lds((const __attribute__((address_space(1))) void*)gb,
                                       (__attribute__((address_space(3))) void*)lb, 16, 0, 0);
    }
    __syncthreads();
    bs8 af[4], bfr[4];
#pragma unroll
    for (int f = 0; f < 4; ++f) {
      af[f]  = *(const bs8*)&As[(wr * 64 + f * 16 + (lane & 15)) * 32 + (lane >> 4) * 8];
      bfr[f] = *(const bs8*)&Bs[(wc * 64 + f * 16 + (lane & 15)) * 32 + (lane >> 4) * 8];
    }
#pragma unroll
    for (int i = 0; i < 4; ++i)
#pragma unroll
      for (int j = 0; j < 4; ++j)
        acc[i][j] = __builtin_amdgcn_mfma_f32_16x16x32_bf16(af[i], bfr[j], acc[i][j], 0, 0, 0);
    __syncthreads();
  }

#pragma unroll
  for (int j = 0; j < 4; ++j) {
    int col = col0 + wc * 64 + j * 16 + (lane & 15);
    float ys = Ys[col];
#pragma unroll
    for (int i = 0; i < 4; ++i) {
#pragma unroll
      for (int q = 0; q < 4; ++q) {
        int row = row0 + wr * 64 + i * 16 + (lane >> 4) * 4 + q;
        float cost = fmaxf(Xs[row] + ys - 2.0f * acc[i][j][q], 0.0f);
        float ks = expf(S_LOG * LN2_ - fminf(cost, 1000.0f) * (1.0f / REG_));
        Km[(size_t)row * N_B + col] = f2fp8(ks);
      }
    }
  }
}

__global__ __launch_bounds__(256) void transpose_fp8(const unsigned char* __restrict__ in,
                                                     unsigned char* __restrict__ out) {
  __shared__ unsigned char t[64][68];
  const int tid = threadIdx.x;
  const int r0 = blockIdx.y * 64, c0 = blockIdx.x * 64;
  {
    int r = tid >> 2, off = (tid & 3) * 16;
    uint4 m = *(const uint4*)&in[(size_t)(r0 + r) * N_B + c0 + off];
    *(uint4*)&t[r][off] = m;
  }
  __syncthreads();
  {
    int j = tid >> 2, off = (tid & 3) * 16;
    unsigned char b[16];
#pragma unroll
    for (int k = 0; k < 16; ++k) b[k] = t[off + k][j];
    *(uint4*)&out[(size_t)(c0 + j) * N_B + r0 + off] = *(uint4*)b;
  }
}

// 2-level device barrier. bar: [0..15]*CSTR group counters, 16*CSTR master,
// 17*CSTR epoch. Monotonic. RELAXED poll (no per-poll invalidate); callers
// get ordering from the single acquire fence at the end (all threads).
__device__ __forceinline__ void gbar(int* bar, int ph) {
  __syncthreads();
  if (threadIdx.x == 0) {
    int g = blockIdx.x & 15;
    int prev = __hip_atomic_fetch_add(&bar[g * CSTR], 1, __ATOMIC_RELEASE,
                                      __HIP_MEMORY_SCOPE_AGENT);
    if (prev == ph * 16 - 1) {
      int pm = __hip_atomic_fetch_add(&bar[16 * CSTR], 1, __ATOMIC_ACQ_REL,
                                      __HIP_MEMORY_SCOPE_AGENT);
      if (pm == ph * 16 - 1) {
        __hip_atomic_store(&bar[17 * CSTR], ph, __ATOMIC_RELEASE,
                           __HIP_MEMORY_SCOPE_AGENT);
      }
    }
    while (__hip_atomic_load(&bar[17 * CSTR], __ATOMIC_RELAXED,
                             __HIP_MEMORY_SCOPE_AGENT) < ph) {
      __builtin_amdgcn_s_sleep(2);
    }
  }
  __syncthreads();
  // one invalidate per thread (vs per poll): orders the plain gathers below.
  __builtin_amdgcn_fence(__ATOMIC_ACQUIRE, "agent");
}

// Persistent Sinkhorn. 256 blocks x 512 threads, 1 block/CU (LDS ~149KB).
__global__ __launch_bounds__(512, 1) void sinkhorn_coop(
    const unsigned char* __restrict__ Krow_g,
    const unsigned char* __restrict__ Kcol_g,
    float* __restrict__ uglob, float* __restrict__ vglob,
    int* __restrict__ bar, float* __restrict__ out) {
  __shared__ unsigned char KrowS[16 * N_B];
  __shared__ unsigned char KcolS[16 * N_B];
  __shared__ _Float16 vsh[N_B];
  __shared__ _Float16 ush[N_B];
  __shared__ float c_lut[256];
  __shared__ float u_loc[16], v_loc[16], lossp[16];
  const int tid = threadIdx.x;
  const int b = blockIdx.x;
  const int wv = tid >> 6, lane = tid & 63;

  {
    const char* ga = (const char*)(Krow_g + (size_t)b * 16 * N_B);
    const char* gb = (const char*)(Kcol_g + (size_t)b * 16 * N_B);
    char* la = (char*)KrowS;
    char* lb = (char*)KcolS;
#pragma unroll
    for (int p = 0; p < 8; ++p) {
      __builtin_amdgcn_global_load_lds(
          (const __attribute__((address_space(1))) void*)(ga + p * 8192 + tid * 16),
          (__attribute__((address_space(3))) void*)(la + p * 8192 + tid * 16), 16, 0, 0);
      __builtin_amdgcn_global_load_lds(
          (const __attribute__((address_space(1))) void*)(gb + p * 8192 + tid * 16),
          (__attribute__((address_space(3))) void*)(lb + p * 8192 + tid * 16), 16, 0, 0);
    }
  }
  if (tid < 256) {
    unsigned short hb = (unsigned short)(tid << 8);
    float kf = __half2float(*(__half*)&hb);
    c_lut[tid] = (kf > 0.f) ? REG_ * (S_LOG * LN2_ - logf(kf)) : 0.f;
  }
  {
    h8 one;
#pragma unroll
    for (int q = 0; q < 8; ++q) one[q] = (_Float16)1.0f;
    *(h8*)&vsh[tid * 8] = one;
  }
  __syncthreads();

  int ph = 0;
  for (int t = 0; t < 50; ++t) {
    const bool last = (t == 49);
    // ---- phase A: u~ for block's 16 rows (4-acc fdot2 chains)
#pragma unroll
    for (int rr = 0; rr < 2; ++rr) {
      const int r = wv * 2 + rr;
      const uint32_t* Kr = (const uint32_t*)&KrowS[r * N_B];
      float a0 = 0.f, a1 = 0.f, a2 = 0.f, a3 = 0.f;
#pragma unroll
      for (int p = 0; p < 16; ++p) {
        uint32_t d = Kr[lane + 64 * p];
        int vb = (lane + 64 * p) * 4;
        h2 v01 = *(const h2*)&vsh[vb];
        h2 v23 = *(const h2*)&vsh[vb + 2];
        h2 k02 = as_h2((d << 8) & 0xFF00FF00u);
        h2 k13 = as_h2(d & 0xFF00FF00u);
        h2 v02 = {v01[0], v23[0]};
        h2 v13 = {v01[1], v23[1]};
        if (p & 1) {
          a2 = __builtin_amdgcn_fdot2(k02, v02, a2, false);
          a3 = __builtin_amdgcn_fdot2(k13, v13, a3, false);
        } else {
          a0 = __builtin_amdgcn_fdot2(k02, v02, a0, false);
          a1 = __builtin_amdgcn_fdot2(k13, v13, a1, false);
        }
      }
      float acc = wave_reduce_sum((a0 + a2) + (a1 + a3));
      if (lane == 0) u_loc[r] = A_SC / (acc + EPS_U);
    }
    __syncthreads();
    // wave 0 lanes 0..15 publish; thread 0's RELEASE arrive drains them.
    if (tid < 16)
      __hip_atomic_store(&uglob[b * 16 + tid], u_loc[tid], __ATOMIC_RELAXED,
                         __HIP_MEMORY_SCOPE_AGENT);
    gbar(bar, ++ph);
    {  // plain vectorized gather (fence in gbar invalidated caches)
      const float4* ug = (const float4*)uglob;
      float4 fa = ug[tid], fb = ug[tid + 512];
      h2 p0 = {(_Float16)fa.x, (_Float16)fa.y}, p1 = {(_Float16)fa.z, (_Float16)fa.w};
      h2 p2 = {(_Float16)fb.x, (_Float16)fb.y}, p3 = {(_Float16)fb.z, (_Float16)fb.w};
      *(h2*)&ush[tid * 4] = p0; *(h2*)&ush[tid * 4 + 2] = p1;
      *(h2*)&ush[2048 + tid * 4] = p2; *(h2*)&ush[2048 + tid * 4 + 2] = p3;
    }
    __syncthreads();

    // ---- phase B: v~ for block's 16 cols
#pragma unroll
    for (int rr = 0; rr < 2; ++rr) {
      const int r = wv * 2 + rr;
      const uint32_t* Kc = (const uint32_t*)&KcolS[r * N_B];
      float a0 = 0.f, a1 = 0.f, a2 = 0.f, a3 = 0.f;
      float tac = 0.f;
#pragma unroll
      for (int p = 0; p < 16; ++p) {
        uint32_t d = Kc[lane + 64 * p];
        int ub = (lane + 64 * p) * 4;
        h2 u01 = *(const h2*)&ush[ub];
        h2 u23 = *(const h2*)&ush[ub + 2];
        h2 k02 = as_h2((d << 8) & 0xFF00FF00u);
        h2 k13 = as_h2(d & 0xFF00FF00u);
        h2 u02 = {u01[0], u23[0]};
        h2 u13 = {u01[1], u23[1]};
        if (p & 1) {
          a2 = __builtin_amdgcn_fdot2(k02, u02, a2, false);
          a3 = __builtin_amdgcn_fdot2(k13, u13, a3, false);
        } else {
          a0 = __builtin_amdgcn_fdot2(k02, u02, a0, false);
          a1 = __builtin_amdgcn_fdot2(k13, u13, a1, false);
        }
        if (last) {
          tac += (float)u01[0] * (float)k02[0] * c_lut[d & 0xFF] +
                 (float)u01[1] * (float)k13[0] * c_lut[(d >> 8) & 0xFF] +
                 (float)u23[0] * (float)k02[1] * c_lut[(d >> 16) & 0xFF] +
                 (float)u23[1] * (float)k13[1] * c_lut[(d >> 24) & 0xFF];
        }
      }
      float acc = wave_reduce_sum((a0 + a2) + (a1 + a3));
      if (!last) {
        if (lane == 0) v_loc[r] = A_SC / (acc + EPS_V);
      } else {
        tac = wave_reduce_sum(tac);
        if (lane == 0) lossp[r] = (A_SC / (acc + EPS_V)) * tac;
      }
    }
    if (!last) {
      __syncthreads();
      if (tid < 16)
        __hip_atomic_store(&vglob[b * 16 + tid], v_loc[tid], __ATOMIC_RELAXED,
                           __HIP_MEMORY_SCOPE_AGENT);
      gbar(bar, ++ph);
      {
        const float4* vg = (const float4*)vglob;
        float4 fa = vg[tid], fb = vg[tid + 512];
        h2 p0 = {(_Float16)fa.x, (_Float16)fa.y}, p1 = {(_Float16)fa.z, (_Float16)fa.w};
        h2 p2 = {(_Float16)fb.x, (_Float16)fb.y}, p3 = {(_Float16)fb.z, (_Float16)fb.w};
        *(h2*)&vsh[tid * 4] = p0; *(h2*)&vsh[tid * 4 + 2] = p1;
        *(h2*)&vsh[2048 + tid * 4] = p2; *(h2*)&vsh[2048 + tid * 4 + 2] = p3;
      }
      __syncthreads();
    }
  }

  __syncthreads();
  if (tid == 0) {
    float s = 0.f;
#pragma unroll
    for (int g = 0; g < 16; ++g) s += lossp[g];
    atomicAdd(out, s * OUT_SCALE);
  }
}

extern "C" void kernel_launch(void* const* d_in, const int* in_sizes, int n_in,
                              void* d_out, int out_size, void* d_ws, size_t ws_size,
                              hipStream_t stream) {
  const float* X = (const float*)d_in[0];
  const float* Y = (const float*)d_in[1];
  float* out = (float*)d_out;
  char* w = (char*)d_ws;

  const size_t MB = 1024 * 1024;
  unsigned char* Km  = (unsigned char*)w;
  unsigned char* KTm = (unsigned char*)(w + 16 * MB);
  int*   bar   = (int*)(w + 32 * MB);                   // 4 KB (zeroed below)
  float* uglob = (float*)(w + 32 * MB + 4096);          // 16 KB
  float* vglob = uglob + N_B;                           // 16 KB
  unsigned short* Xe = (unsigned short*)(w + 33 * MB);
  unsigned short* Ye = (unsigned short*)(w + 48 * MB);
  float* Xs = (float*)(w + 64 * MB);
  float* Ys = Xs + N_B;

  hipMemsetAsync(d_out, 0, sizeof(float), stream);
  hipMemsetAsync(bar, 0, 4096, stream);

  prep_kernel<<<N_B * N_D / (256 * 8), 256, 0, stream>>>(X, Y, Xe, Ye);
  rownorm_kernel<<<N_B / 4, 256, 0, stream>>>(X, Xs);
  rownorm_kernel<<<N_B / 4, 256, 0, stream>>>(Y, Ys);

  gemm_costK<<<dim3(32, 32), 256, 0, stream>>>(Xe, Ye, Xs, Ys, Km);
  transpose_fp8<<<dim3(64, 64), 256, 0, stream>>>(Km, KTm);

  void* kargs[] = {(void*)&Km, (void*)&KTm, (void*)&uglob, (void*)&vglob,
                   (void*)&bar, (void*)&out};
  hipLaunchCooperativeKernel((void*)sinkhorn_coop, dim3(256), dim3(512), kargs, 0, stream);
}

// Round 15
// 616.136 us; speedup vs baseline: 3.4073x; 3.4073x over previous
//
#include <hip/hip_runtime.h>
#include <hip/hip_fp16.h>
#include <cstdint>
#include <cstddef>

// Sinkhorn OT loss, B=4096, D=512.
// Round 15: revert to r5 multi-launch structure (best: 797us). Changes:
//  1. gemm KE=1024 (Xe=[hi|lo], Ye=[yh|yh] -> dot = x . yh exactly)
//  2. matvec: 512 blocks, v staged in LDS, 2 rows/wave sharing x reads
//  3. last v-update + loss fused into one KT pass; v-init folded into rownorm
// Scaling (r5, passed): Ks = K*2^28 fp8 e5m2; u' = INV_N/(Ks v + 1e-9);
// gamma = u' Ks v'; cost = REG*(28 ln2 - ln Ks) via byte LUT.
// ws: Km 16MB @0 | KTm @16MB | Xe 8MB @32MB | Ye 8MB @40MB |
//     Xs,Ys,u,v @48MB

#define N_B 4096
#define N_D 512
#define KE  1024
#define REG_ 0.05f
#define EPS_ 1e-9f
#define INV_N (1.0f / 4096.0f)
#define SCALE_LOG 28.0f
#define LN2_ 0.69314718f

typedef __attribute__((ext_vector_type(8))) short bs8;
typedef __attribute__((ext_vector_type(8))) unsigned short us8;
typedef __attribute__((ext_vector_type(4))) float f32x4;

__device__ __forceinline__ float bf2f(unsigned short u) {
  union { uint32_t i; float f; } x; x.i = ((uint32_t)u) << 16; return x.f;
}
__device__ __forceinline__ unsigned short f2bf(float f) {
  union { float f; uint32_t i; } x; x.f = f;
  uint32_t r = (x.i + 0x7FFFu + ((x.i >> 16) & 1u)) >> 16;
  return (unsigned short)r;
}
// e5m2 = top byte of fp16 (RNE). Clamp so rounding can't hit inf.
__device__ __forceinline__ unsigned char f2fp8(float f) {
  f = fminf(f, 57344.0f);
  __half h = __float2half(f);
  unsigned short hb = *(unsigned short*)&h;
  unsigned short r = (unsigned short)((hb + 0x7F + ((hb >> 8) & 1)) >> 8);
  return (unsigned char)r;
}
__device__ __forceinline__ float fp82f(uint32_t b) {
  unsigned short hb = (unsigned short)(b << 8);
  __half h = *(__half*)&hb;
  return __half2float(h);
}
__device__ __forceinline__ float wave_reduce_sum(float x) {
#pragma unroll
  for (int off = 32; off > 0; off >>= 1) x += __shfl_down(x, off);
  return x;
}

// Xe = [hi | lo], Ye = [yh | yh]: sum over KE=1024 gives
// (xh+xl).yh = x . yh exactly; only Y-rounding error remains (~1e-4 on cost).
__global__ __launch_bounds__(256) void prep_kernel(const float* __restrict__ X,
                                                   const float* __restrict__ Y,
                                                   unsigned short* __restrict__ Xe,
                                                   unsigned short* __restrict__ Ye) {
  int idx = (blockIdx.x * 256 + threadIdx.x) * 8;
  int row = idx >> 9, col = idx & 511;
  size_t base = (size_t)row * KE + col;
  float fx[8], fy[8];
  *(float4*)&fx[0] = *(const float4*)&X[idx];
  *(float4*)&fx[4] = *(const float4*)&X[idx + 4];
  *(float4*)&fy[0] = *(const float4*)&Y[idx];
  *(float4*)&fy[4] = *(const float4*)&Y[idx + 4];
  us8 xh, xl, yh;
#pragma unroll
  for (int k = 0; k < 8; ++k) {
    unsigned short h = f2bf(fx[k]);
    xh[k] = h; xl[k] = f2bf(fx[k] - bf2f(h));
    yh[k] = f2bf(fy[k]);
  }
  *(us8*)&Xe[base] = xh; *(us8*)&Xe[base + 512] = xl;
  *(us8*)&Ye[base] = yh; *(us8*)&Ye[base + 512] = yh;
}

// rownorm; optionally initializes vinit[row]=1 (folds init_v dispatch).
__global__ __launch_bounds__(256) void rownorm_kernel(const float* __restrict__ X,
                                                      float* __restrict__ out,
                                                      float* __restrict__ vinit) {
  int row = blockIdx.x * 4 + (threadIdx.x >> 6);
  int lane = threadIdx.x & 63;
  const float4* Xr = (const float4*)(X + (size_t)row * N_D);
  float acc = 0.f;
#pragma unroll
  for (int k = lane; k < N_D / 4; k += 64) {
    float4 a = Xr[k];
    acc += a.x * a.x + a.y * a.y + a.z * a.z + a.w * a.w;
  }
  acc = wave_reduce_sum(acc);
  if (lane == 0) {
    out[row] = acc;
    if (vinit) vinit[row] = 1.0f;
  }
}

// 128x128-tile MFMA GEMM over KE=1024; epilogue -> fp8 Ks = K*2^28.
__global__ __launch_bounds__(256) void gemm_costK(const unsigned short* __restrict__ Xe,
                                                  const unsigned short* __restrict__ Ye,
                                                  const float* __restrict__ Xs,
                                                  const float* __restrict__ Ys,
                                                  unsigned char* __restrict__ Km) {
  __shared__ unsigned short As[128 * 32];
  __shared__ unsigned short Bs[128 * 32];
  const int tid = threadIdx.x;
  const int lane = tid & 63, w = tid >> 6;
  const int wr = w >> 1, wc = w & 1;
  const int row0 = blockIdx.y * 128, col0 = blockIdx.x * 128;

  f32x4 acc[4][4];
#pragma unroll
  for (int i = 0; i < 4; ++i)
#pragma unroll
    for (int j = 0; j < 4; ++j) acc[i][j] = (f32x4)(0.0f);

  const int srow = tid >> 2;
  const int scol = (tid & 3) * 8;

  for (int k0 = 0; k0 < KE; k0 += 32) {
#pragma unroll
    for (int c = 0; c < 2; ++c) {
      int r = srow + c * 64;
      const unsigned short* ga = Xe + (size_t)(row0 + r) * KE + k0 + scol;
      const unsigned short* gb = Ye + (size_t)(col0 + r) * KE + k0 + scol;
      char* la = (char*)As + c * 4096 + w * 1024;
      char* lb = (char*)Bs + c * 4096 + w * 1024;
      __builtin_amdgcn_global_load_lds((const __attribute__((address_space(1))) void*)ga,
                                       (__attribute__((address_space(3))) void*)la, 16, 0, 0);
      __builtin_amdgcn_global_load_lds((const __attribute__((address_space(1))) void*)gb,
                                       (__attribute__((address_space(3))) void*)lb, 16, 0, 0);
    }
    __syncthreads();
    bs8 af[4], bfr[4];
#pragma unroll
    for (int f = 0; f < 4; ++f) {
      af[f]  = *(const bs8*)&As[(wr * 64 + f * 16 + (lane & 15)) * 32 + (lane >> 4) * 8];
      bfr[f] = *(const bs8*)&Bs[(wc * 64 + f * 16 + (lane & 15)) * 32 + (lane >> 4) * 8];
    }
#pragma unroll
    for (int i = 0; i < 4; ++i)
#pragma unroll
      for (int j = 0; j < 4; ++j)
        acc[i][j] = __builtin_amdgcn_mfma_f32_16x16x32_bf16(af[i], bfr[j], acc[i][j], 0, 0, 0);
    __syncthreads();
  }

#pragma unroll
  for (int j = 0; j < 4; ++j) {
    int col = col0 + wc * 64 + j * 16 + (lane & 15);
    float ys = Ys[col];
#pragma unroll
    for (int i = 0; i < 4; ++i) {
#pragma unroll
      for (int q = 0; q < 4; ++q) {
        int row = row0 + wr * 64 + i * 16 + (lane >> 4) * 4 + q;
        float cost = fmaxf(Xs[row] + ys - 2.0f * acc[i][j][q], 0.0f);
        float ks = expf(SCALE_LOG * LN2_ - fminf(cost, 1000.0f) * (1.0f / REG_));
        Km[(size_t)row * N_B + col] = f2fp8(ks);
      }
    }
  }
}

__global__ __launch_bounds__(256) void transpose_fp8(const unsigned char* __restrict__ in,
                                                     unsigned char* __restrict__ out) {
  __shared__ unsigned char t[64][68];
  const int tid = threadIdx.x;
  const int r0 = blockIdx.y * 64, c0 = blockIdx.x * 64;
  {
    int r = tid >> 2, off = (tid & 3) * 16;
    uint4 m = *(const uint4*)&in[(size_t)(r0 + r) * N_B + c0 + off];
    *(uint4*)&t[r][off] = m;
  }
  __syncthreads();
  {
    int j = tid >> 2, off = (tid & 3) * 16;
    unsigned char b[16];
#pragma unroll
    for (int k = 0; k < 16; ++k) b[k] = t[off + k][j];
    *(uint4*)&out[(size_t)(c0 + j) * N_B + r0 + off] = *(uint4*)b;
  }
}

// 512 blocks x 256 thr; block stages x (16KB) in LDS; wave handles 2 rows
// sharing the staged x reads. out[row] = scale/(dot+eps).
__global__ __launch_bounds__(256) void matvec_fp8(const unsigned char* __restrict__ M,
                                                  const float* __restrict__ x,
                                                  float* __restrict__ out, float scale) {
  __shared__ float4 xs[N_B / 4];
  const int tid = threadIdx.x;
  for (int k = tid; k < N_B / 4; k += 256) xs[k] = ((const float4*)x)[k];
  __syncthreads();
  const int wv = tid >> 6, lane = tid & 63;
  const int r0 = blockIdx.x * 8 + wv * 2;
  const uint4* M0 = (const uint4*)(M + (size_t)r0 * N_B);
  const uint4* M1 = (const uint4*)(M + (size_t)(r0 + 1) * N_B);
  float a0 = 0.f, a1 = 0.f;
#pragma unroll
  for (int it = 0; it < 4; ++it) {
    int c = it * 64 + lane;
    uint4 m0 = M0[c], m1 = M1[c];
    float4 x0 = xs[c * 4], x1 = xs[c * 4 + 1], x2 = xs[c * 4 + 2], x3 = xs[c * 4 + 3];
    a0 += fp82f(m0.x & 0xFF) * x0.x + fp82f((m0.x >> 8) & 0xFF) * x0.y +
          fp82f((m0.x >> 16) & 0xFF) * x0.z + fp82f(m0.x >> 24) * x0.w +
          fp82f(m0.y & 0xFF) * x1.x + fp82f((m0.y >> 8) & 0xFF) * x1.y +
          fp82f((m0.y >> 16) & 0xFF) * x1.z + fp82f(m0.y >> 24) * x1.w +
          fp82f(m0.z & 0xFF) * x2.x + fp82f((m0.z >> 8) & 0xFF) * x2.y +
          fp82f((m0.z >> 16) & 0xFF) * x2.z + fp82f(m0.z >> 24) * x2.w +
          fp82f(m0.w & 0xFF) * x3.x + fp82f((m0.w >> 8) & 0xFF) * x3.y +
          fp82f((m0.w >> 16) & 0xFF) * x3.z + fp82f(m0.w >> 24) * x3.w;
    a1 += fp82f(m1.x & 0xFF) * x0.x + fp82f((m1.x >> 8) & 0xFF) * x0.y +
          fp82f((m1.x >> 16) & 0xFF) * x0.z + fp82f(m1.x >> 24) * x0.w +
          fp82f(m1.y & 0xFF) * x1.x + fp82f((m1.y >> 8) & 0xFF) * x1.y +
          fp82f((m1.y >> 16) & 0xFF) * x1.z + fp82f(m1.y >> 24) * x1.w +
          fp82f(m1.z & 0xFF) * x2.x + fp82f((m1.z >> 8) & 0xFF) * x2.y +
          fp82f((m1.z >> 16) & 0xFF) * x2.z + fp82f(m1.z >> 24) * x2.w +
          fp82f(m1.w & 0xFF) * x3.x + fp82f((m1.w >> 8) & 0xFF) * x3.y +
          fp82f((m1.w >> 16) & 0xFF) * x3.z + fp82f(m1.w >> 24) * x3.w;
  }
  a0 = wave_reduce_sum(a0);
  a1 = wave_reduce_sum(a1);
  if (lane == 0) {
    out[r0] = scale / (a0 + EPS_);
    out[r0 + 1] = scale / (a1 + EPS_);
  }
}

// Final fused: one KT pass computing s_j (v-denominator) AND
// t_j = sum_i u_i Ks_ij c_ij; adds sum_j v_j t_j into out.
__global__ __launch_bounds__(256) void final_fused(const unsigned char* __restrict__ KT,
                                                   const float* __restrict__ u,
                                                   float* __restrict__ out) {
  __shared__ float4 xs[N_B / 4];
  __shared__ float c_lut[256];
  __shared__ float lossp[4];
  const int tid = threadIdx.x;
  for (int k = tid; k < N_B / 4; k += 256) xs[k] = ((const float4*)u)[k];
  if (tid < 256) {
    float kf = fp82f((uint32_t)tid);
    c_lut[tid] = (kf > 0.f) ? REG_ * (SCALE_LOG * LN2_ - logf(kf)) : 0.f;
  }
  __syncthreads();
  const int wv = tid >> 6, lane = tid & 63;
  float wloss = 0.f;
#pragma unroll
  for (int rr = 0; rr < 2; ++rr) {
    const int r = blockIdx.x * 8 + wv * 2 + rr;
    const uint4* Mr = (const uint4*)(KT + (size_t)r * N_B);
    float s = 0.f, t = 0.f;
#pragma unroll
    for (int it = 0; it < 4; ++it) {
      int c = it * 64 + lane;
      uint4 m = Mr[c];
      float4 x0 = xs[c * 4], x1 = xs[c * 4 + 1], x2 = xs[c * 4 + 2], x3 = xs[c * 4 + 3];
      uint32_t parts[4] = {m.x, m.y, m.z, m.w};
      const float* xv[4] = {&x0.x, &x1.x, &x2.x, &x3.x};
#pragma unroll
      for (int p = 0; p < 4; ++p) {
#pragma unroll
        for (int e = 0; e < 4; ++e) {
          uint32_t byte = (parts[p] >> (8 * e)) & 0xFF;
          float kf = fp82f(byte);
          float uk = xv[p][e] * kf;
          s += uk;
          t += uk * c_lut[byte];
        }
      }
    }
    s = wave_reduce_sum(s);
    t = wave_reduce_sum(t);
    if (lane == 0) wloss += (INV_N / (s + EPS_)) * t;
  }
  if (lane == 0) lossp[wv] = wloss;
  __syncthreads();
  if (tid == 0) atomicAdd(out, lossp[0] + lossp[1] + lossp[2] + lossp[3]);
}

extern "C" void kernel_launch(void* const* d_in, const int* in_sizes, int n_in,
                              void* d_out, int out_size, void* d_ws, size_t ws_size,
                              hipStream_t stream) {
  const float* X = (const float*)d_in[0];
  const float* Y = (const float*)d_in[1];
  float* out = (float*)d_out;
  char* w = (char*)d_ws;

  const size_t MB = 1024 * 1024;
  unsigned char* Km  = (unsigned char*)w;
  unsigned char* KTm = (unsigned char*)(w + 16 * MB);
  unsigned short* Xe = (unsigned short*)(w + 32 * MB);  // 8 MB
  unsigned short* Ye = (unsigned short*)(w + 40 * MB);  // 8 MB
  float* Xs = (float*)(w + 48 * MB);
  float* Ys = Xs + N_B;
  float* u  = Ys + N_B;
  float* v  = u + N_B;

  hipMemsetAsync(d_out, 0, sizeof(float), stream);

  prep_kernel<<<N_B * N_D / (256 * 8), 256, 0, stream>>>(X, Y, Xe, Ye);
  rownorm_kernel<<<N_B / 4, 256, 0, stream>>>(X, Xs, nullptr);
  rownorm_kernel<<<N_B / 4, 256, 0, stream>>>(Y, Ys, v);  // also v=1

  gemm_costK<<<dim3(32, 32), 256, 0, stream>>>(Xe, Ye, Xs, Ys, Km);
  transpose_fp8<<<dim3(64, 64), 256, 0, stream>>>(Km, KTm);

  for (int it = 0; it < 50; ++it) {
    matvec_fp8<<<N_B / 8, 256, 0, stream>>>(Km, v, u, INV_N);
    if (it < 49)
      matvec_fp8<<<N_B / 8, 256, 0, stream>>>(KTm, u, v, INV_N);
  }
  final_fused<<<N_B / 8, 256, 0, stream>>>(KTm, u, out);
}